// Round 1
// baseline (365.925 us; speedup 1.0000x reference)
//
#include <hip/hip_runtime.h>

// Problem constants (match reference)
#define BB 32
#define NN 25200
#define MM 200
#define CC 80

constexpr float EPSF = 1e-7f;
constexpr float L_COORD = 5.0f;
constexpr float L_NOOBJ = 0.5f;

// work-item layout
constexpr int ITEMS_GIOU = BB * MM;            // 6400
constexpr int ITEMS_CLS  = BB * MM;            // 6400
constexpr int ITEMS_OBJ  = BB * NN;            // 806400
constexpr int ITEMS_TOTAL = ITEMS_GIOU + ITEMS_CLS + ITEMS_OBJ;

constexpr int BLOCK = 256;
constexpr int GRID  = 1024;

__device__ __forceinline__ float softplus_f(float x) {
    // log(1 + e^x), stable: max(x,0) + log1p(exp(-|x|))
    return fmaxf(x, 0.0f) + log1pf(expf(-fabsf(x)));
}

__global__ __launch_bounds__(BLOCK)
void detloss_kernel(const float* __restrict__ pred_bbox,   // (B, N, 4)
                    const float* __restrict__ pred_obj,    // (B, N)
                    const float* __restrict__ pred_cls,    // (B, N, C)
                    const float* __restrict__ gt_boxes,    // (B, M, 4)
                    const int*   __restrict__ gt_labels,   // (B, M)
                    float* __restrict__ out,               // 4 floats
                    float* __restrict__ ws)                // ws[0..2] sums, ws[3] ticket
{
    float s_bbox = 0.0f, s_obj = 0.0f, s_cls = 0.0f;

    const int stride = GRID * BLOCK;
    for (int i = blockIdx.x * BLOCK + threadIdx.x; i < ITEMS_TOTAL; i += stride) {
        if (i < ITEMS_GIOU) {
            // ---- GIoU for pair (b, m) ----
            const int b = i / MM, m = i - b * MM;
            const float4 p = *(const float4*)(pred_bbox + ((size_t)b * NN + m) * 4);
            const float4 t = *(const float4*)(gt_boxes + (size_t)i * 4);
            const float px1 = p.x - p.z * 0.5f, py1 = p.y - p.w * 0.5f;
            const float px2 = p.x + p.z * 0.5f, py2 = p.y + p.w * 0.5f;
            const float tx1 = t.x - t.z * 0.5f, ty1 = t.y - t.w * 0.5f;
            const float tx2 = t.x + t.z * 0.5f, ty2 = t.y + t.w * 0.5f;
            const float ix1 = fmaxf(px1, tx1), iy1 = fmaxf(py1, ty1);
            const float ix2 = fminf(px2, tx2), iy2 = fminf(py2, ty2);
            const float inter = fmaxf(ix2 - ix1, 0.0f) * fmaxf(iy2 - iy1, 0.0f);
            const float uni = (px2 - px1) * (py2 - py1)
                            + (tx2 - tx1) * (ty2 - ty1) - inter;
            const float iou = inter / (uni + EPSF);
            const float ex1 = fminf(px1, tx1), ey1 = fminf(py1, ty1);
            const float ex2 = fmaxf(px2, tx2), ey2 = fmaxf(py2, ty2);
            const float enc = (ex2 - ex1) * (ey2 - ey1);
            s_bbox += 1.0f - (iou - (enc - uni) / (enc + EPSF));
        } else if (i < ITEMS_GIOU + ITEMS_CLS) {
            // ---- cls NLL for row (b, m): lse(row) - row[label] ----
            const int r = i - ITEMS_GIOU;
            const int b = r / MM, m = r - b * MM;
            const float* row = pred_cls + ((size_t)b * NN + m) * CC;
            float mx = -INFINITY;
            float v[CC];
            #pragma unroll 4
            for (int c = 0; c < CC; ++c) { v[c] = row[c]; mx = fmaxf(mx, v[c]); }
            float se = 0.0f;
            #pragma unroll 4
            for (int c = 0; c < CC; ++c) se += expf(v[c] - mx);
            const float lse = mx + logf(se);
            const int lbl = gt_labels[r];
            s_cls += lse - v[lbl];
        } else {
            // ---- objectness element e over (B, N) ----
            const int e = i - (ITEMS_GIOU + ITEMS_CLS);
            const int n = e % NN;
            const float x = pred_obj[e];
            if (n < MM) s_obj += softplus_f(-x) * (1.0f / (float)(BB * MM));
            else        s_obj += softplus_f(x) * (L_NOOBJ / (float)(BB * (NN - MM)));
        }
    }

    // ---- wave (64-lane) shuffle reduce ----
    #pragma unroll
    for (int off = 32; off > 0; off >>= 1) {
        s_bbox += __shfl_down(s_bbox, off, 64);
        s_obj  += __shfl_down(s_obj,  off, 64);
        s_cls  += __shfl_down(s_cls,  off, 64);
    }

    __shared__ float red[3][BLOCK / 64];
    const int wave = threadIdx.x >> 6;
    const int lane = threadIdx.x & 63;
    if (lane == 0) {
        red[0][wave] = s_bbox;
        red[1][wave] = s_obj;
        red[2][wave] = s_cls;
    }
    __syncthreads();

    if (threadIdx.x == 0) {
        float tb = 0.0f, to = 0.0f, tc = 0.0f;
        #pragma unroll
        for (int w = 0; w < BLOCK / 64; ++w) {
            tb += red[0][w]; to += red[1][w]; tc += red[2][w];
        }
        atomicAdd(&ws[0], tb);
        atomicAdd(&ws[1], to);
        atomicAdd(&ws[2], tc);
        __threadfence();
        const unsigned ticket = atomicAdd((unsigned*)&ws[3], 1u);
        if (ticket == (unsigned)(gridDim.x - 1)) {
            // last block: all other blocks' atomics are visible (device-scope)
            const float sb = atomicAdd(&ws[0], 0.0f);
            const float so = atomicAdd(&ws[1], 0.0f);
            const float sc = atomicAdd(&ws[2], 0.0f);
            const float loss_bbox = sb * (L_COORD / (float)(BB * MM));
            const float loss_obj  = so;  // already weighted per element
            const float loss_cls  = sc * (1.0f / (float)(BB * MM));
            out[0] = loss_bbox + loss_obj + loss_cls;
            out[1] = loss_bbox;
            out[2] = loss_obj;
            out[3] = loss_cls;
        }
    }
}

extern "C" void kernel_launch(void* const* d_in, const int* in_sizes, int n_in,
                              void* d_out, int out_size, void* d_ws, size_t ws_size,
                              hipStream_t stream) {
    const float* pred_bbox = (const float*)d_in[0];
    const float* pred_obj  = (const float*)d_in[1];
    const float* pred_cls  = (const float*)d_in[2];
    const float* gt_boxes  = (const float*)d_in[3];
    const int*   gt_labels = (const int*)d_in[4];
    float* out = (float*)d_out;
    float* ws  = (float*)d_ws;

    // ws[0..2] = loss sums, ws[3] = finalize ticket counter (poisoned 0xAA each call)
    hipMemsetAsync(ws, 0, 4 * sizeof(float), stream);
    detloss_kernel<<<GRID, BLOCK, 0, stream>>>(pred_bbox, pred_obj, pred_cls,
                                               gt_boxes, gt_labels, out, ws);
}

// Round 2
// 295.613 us; speedup vs baseline: 1.2379x; 1.2379x over previous
//
#include <hip/hip_runtime.h>

// Problem constants (match reference)
#define BB 32
#define NN 25200
#define MM 200
#define CC 80

constexpr float EPSF = 1e-7f;
constexpr float L_COORD = 5.0f;

constexpr int BLOCK = 256;
constexpr int GRID  = 1024;

// virtual work-item space (all region boundaries are multiples of 64 so every
// wave lives entirely in one region, and 16-lane cls groups stay wave-aligned)
constexpr int R_GIOU = BB * MM;                  // 6400 items, 1 thread each
constexpr int R_CLS  = R_GIOU + BB * MM * 16;    // 6400 rows * 16 lanes = 102400
constexpr int R_OBJ  = R_CLS + (BB * NN) / 4;    // 201600 float4 items
// totals: 6400 % 64 == 0, 108800 % 64 == 0, 310400 % 64 == 0  ✓

constexpr float W_POS = 1.0f / (float)(BB * MM);            // 1/6400
constexpr float W_NEG = 0.5f / (float)(BB * (NN - MM));     // 0.5/800000

__device__ __forceinline__ float softplus_f(float x) {
    // log(1 + e^x), stable: max(x,0) + log(1 + exp(-|x|)); fast intrinsics
    return fmaxf(x, 0.0f) + __logf(1.0f + __expf(-fabsf(x)));
}

__global__ __launch_bounds__(BLOCK)
void detloss_partials(const float* __restrict__ pred_bbox,   // (B, N, 4)
                      const float* __restrict__ pred_obj,    // (B, N)
                      const float* __restrict__ pred_cls,    // (B, N, C)
                      const float* __restrict__ gt_boxes,    // (B, M, 4)
                      const int*   __restrict__ gt_labels,   // (B, M)
                      float* __restrict__ ws)                // [3*GRID] partials
{
    float s_bbox = 0.0f, s_obj = 0.0f, s_cls = 0.0f;

    const int stride = GRID * BLOCK;
    for (int i = blockIdx.x * BLOCK + threadIdx.x; i < R_OBJ; i += stride) {
        if (i < R_GIOU) {
            // ---- GIoU for pair (b, m), one thread each ----
            const int b = i / MM, m = i - b * MM;
            const float4 p = *(const float4*)(pred_bbox + ((size_t)b * NN + m) * 4);
            const float4 t = *(const float4*)(gt_boxes + (size_t)i * 4);
            const float px1 = p.x - p.z * 0.5f, py1 = p.y - p.w * 0.5f;
            const float px2 = p.x + p.z * 0.5f, py2 = p.y + p.w * 0.5f;
            const float tx1 = t.x - t.z * 0.5f, ty1 = t.y - t.w * 0.5f;
            const float tx2 = t.x + t.z * 0.5f, ty2 = t.y + t.w * 0.5f;
            const float ix1 = fmaxf(px1, tx1), iy1 = fmaxf(py1, ty1);
            const float ix2 = fminf(px2, tx2), iy2 = fminf(py2, ty2);
            const float inter = fmaxf(ix2 - ix1, 0.0f) * fmaxf(iy2 - iy1, 0.0f);
            const float uni = (px2 - px1) * (py2 - py1)
                            + (tx2 - tx1) * (ty2 - ty1) - inter;
            const float iou = inter / (uni + EPSF);
            const float ex1 = fminf(px1, tx1), ey1 = fminf(py1, ty1);
            const float ex2 = fmaxf(px2, tx2), ey2 = fmaxf(py2, ty2);
            const float enc = (ex2 - ex1) * (ey2 - ey1);
            s_bbox += 1.0f - (iou - (enc - uni) / (enc + EPSF));
        } else if (i < R_CLS) {
            // ---- cls NLL: 16-lane group per row, lane j reads row[j + 16k] ----
            const int q   = i - R_GIOU;
            const int r   = q >> 4;        // row id in [0, 6400)
            const int sub = q & 15;        // lane within group
            const int b = r / MM, m = r - b * MM;
            const float* row = pred_cls + ((size_t)b * NN + m) * CC;
            float v0 = row[sub];
            float v1 = row[sub + 16];
            float v2 = row[sub + 32];
            float v3 = row[sub + 48];
            float v4 = row[sub + 64];
            float mx = fmaxf(fmaxf(fmaxf(v0, v1), fmaxf(v2, v3)), v4);
            #pragma unroll
            for (int off = 1; off < 16; off <<= 1)
                mx = fmaxf(mx, __shfl_xor(mx, off, 16));
            float se = __expf(v0 - mx) + __expf(v1 - mx) + __expf(v2 - mx)
                     + __expf(v3 - mx) + __expf(v4 - mx);
            #pragma unroll
            for (int off = 1; off < 16; off <<= 1)
                se += __shfl_xor(se, off, 16);
            if (sub == 0) {
                const float lse = mx + __logf(se);
                const int lbl = gt_labels[r];
                s_cls += lse - row[lbl];   // row[lbl] is L1-hot
            }
        } else {
            // ---- objectness, float4 per item; MM,NN divisible by 4 so the
            //      whole float4 shares one pos/neg classification ----
            const int o = i - R_CLS;
            const int e = o * 4;                 // flat element base in (B*N)
            const int n = e % NN;                // position within row
            const float4 x = *(const float4*)(pred_obj + e);
            if (n < MM) {
                s_obj += W_POS * (softplus_f(-x.x) + softplus_f(-x.y)
                                + softplus_f(-x.z) + softplus_f(-x.w));
            } else {
                s_obj += W_NEG * (softplus_f(x.x) + softplus_f(x.y)
                                + softplus_f(x.z) + softplus_f(x.w));
            }
        }
    }

    // ---- wave (64-lane) shuffle reduce ----
    #pragma unroll
    for (int off = 32; off > 0; off >>= 1) {
        s_bbox += __shfl_down(s_bbox, off, 64);
        s_obj  += __shfl_down(s_obj,  off, 64);
        s_cls  += __shfl_down(s_cls,  off, 64);
    }

    __shared__ float red[3][BLOCK / 64];
    const int wave = threadIdx.x >> 6;
    const int lane = threadIdx.x & 63;
    if (lane == 0) {
        red[0][wave] = s_bbox;
        red[1][wave] = s_obj;
        red[2][wave] = s_cls;
    }
    __syncthreads();

    if (threadIdx.x == 0) {
        float tb = 0.0f, to = 0.0f, tc = 0.0f;
        #pragma unroll
        for (int w = 0; w < BLOCK / 64; ++w) {
            tb += red[0][w]; to += red[1][w]; tc += red[2][w];
        }
        // disjoint slots -> plain stores, no init, no atomics
        ws[blockIdx.x]            = tb;
        ws[GRID + blockIdx.x]     = to;
        ws[2 * GRID + blockIdx.x] = tc;
    }
}

__global__ __launch_bounds__(BLOCK)
void detloss_finalize(const float* __restrict__ ws, float* __restrict__ out) {
    float tb = 0.0f, to = 0.0f, tc = 0.0f;
    for (int p = threadIdx.x; p < GRID; p += BLOCK) {
        tb += ws[p];
        to += ws[GRID + p];
        tc += ws[2 * GRID + p];
    }
    #pragma unroll
    for (int off = 32; off > 0; off >>= 1) {
        tb += __shfl_down(tb, off, 64);
        to += __shfl_down(to, off, 64);
        tc += __shfl_down(tc, off, 64);
    }
    __shared__ float red[3][BLOCK / 64];
    const int wave = threadIdx.x >> 6;
    const int lane = threadIdx.x & 63;
    if (lane == 0) { red[0][wave] = tb; red[1][wave] = to; red[2][wave] = tc; }
    __syncthreads();
    if (threadIdx.x == 0) {
        float sb = 0.0f, so = 0.0f, sc = 0.0f;
        #pragma unroll
        for (int w = 0; w < BLOCK / 64; ++w) {
            sb += red[0][w]; so += red[1][w]; sc += red[2][w];
        }
        const float loss_bbox = sb * (L_COORD / (float)(BB * MM));
        const float loss_obj  = so;                       // weighted per element
        const float loss_cls  = sc * (1.0f / (float)(BB * MM));
        out[0] = loss_bbox + loss_obj + loss_cls;
        out[1] = loss_bbox;
        out[2] = loss_obj;
        out[3] = loss_cls;
    }
}

extern "C" void kernel_launch(void* const* d_in, const int* in_sizes, int n_in,
                              void* d_out, int out_size, void* d_ws, size_t ws_size,
                              hipStream_t stream) {
    const float* pred_bbox = (const float*)d_in[0];
    const float* pred_obj  = (const float*)d_in[1];
    const float* pred_cls  = (const float*)d_in[2];
    const float* gt_boxes  = (const float*)d_in[3];
    const int*   gt_labels = (const int*)d_in[4];
    float* out = (float*)d_out;
    float* ws  = (float*)d_ws;   // uses 3*GRID*4 = 12 KB of scratch

    detloss_partials<<<GRID, BLOCK, 0, stream>>>(pred_bbox, pred_obj, pred_cls,
                                                 gt_boxes, gt_labels, ws);
    detloss_finalize<<<1, BLOCK, 0, stream>>>(ws, out);
}